// Round 10
// baseline (3678.959 us; speedup 1.0000x reference)
//
#include <hip/hip_runtime.h>
#include <math.h>

// Persistent-kernel NTM, R21 = R20 + count-gated value polls (storm kill).
// Theory: mass tag-polling (512 thr x 128 blk spinning agent loads) saturates
// the coherence point and slows the LAST publisher's compute -> inflates every
// value-hop. Fix (additive): publishers bump a per-step count (hcnt after h,
// pcnt0/pcnt1 after C batch0/batch1); consumers have tid0 poll the single
// count line to 128, then run the existing tag-checked reads (~1 iteration).
// Tags retained -> no new ordering requirements; arithmetic bit-identical.

#define NBLK 128
#define NTHR 512
#define Msz  16384
#define Dsz  256
#define Hsz  512
#define Isz  256
#define Tlen 128
#define RPB  128
#define NG   16

#define CNT1 (1ull << 48)

struct Params { const float* in[34]; float* out; float* ws; };

__device__ __forceinline__ float wred64(float v){
#pragma unroll
  for (int o = 32; o > 0; o >>= 1) v += __shfl_xor(v, o, 64);
  return v;
}
__device__ __forceinline__ float wred32(float v){
#pragma unroll
  for (int o = 16; o > 0; o >>= 1) v += __shfl_xor(v, o, 32);
  return v;
}
// sum over each 4-lane quad via DPP quad_perm (no DS ops, no bank conflicts)
__device__ __forceinline__ float qsum4(float v){
  v += __uint_as_float(__builtin_amdgcn_mov_dpp(__float_as_uint(v), 0xB1, 0xF, 0xF, true)); // xor1
  v += __uint_as_float(__builtin_amdgcn_mov_dpp(__float_as_uint(v), 0x4E, 0xF, 0xF, true)); // xor2
  return v;
}
__device__ __forceinline__ float sigm(float x){ return 1.f / (1.f + __expf(-x)); }
__device__ __forceinline__ float softplusf(float x){ return (x > 20.f) ? x : log1pf(__expf(x)); }

__device__ __forceinline__ void gstore(float* p, float v){
  __hip_atomic_store(p, v, __ATOMIC_RELAXED, __HIP_MEMORY_SCOPE_AGENT);
}
__device__ __forceinline__ float gload(const float* p){
  return __hip_atomic_load(p, __ATOMIC_RELAXED, __HIP_MEMORY_SCOPE_AGENT);
}
__device__ __forceinline__ void gstore64(unsigned long long* p, unsigned long long v){
  __hip_atomic_store(p, v, __ATOMIC_RELAXED, __HIP_MEMORY_SCOPE_AGENT);
}
__device__ __forceinline__ unsigned long long gload64(const unsigned long long* p){
  return __hip_atomic_load(p, __ATOMIC_RELAXED, __HIP_MEMORY_SCOPE_AGENT);
}
// lgkmcnt(0)-only barrier: vmcnt=63, expcnt=7, lgkmcnt=0 -> imm 0xC07F
__device__ __forceinline__ void lbar(){
  __builtin_amdgcn_s_waitcnt(0xC07F);
  __builtin_amdgcn_s_barrier();
}
// poll a tagged word until tag >= want; return payload float
__device__ __forceinline__ float pollw(const unsigned long long* p, unsigned want){
  unsigned long long k;
  do { k = gload64(p); } while ((int)((unsigned)(k >> 32) - want) < 0);
  return __uint_as_float((unsigned)k);
}
// fixed-point publish word: count 1 in bits 48+, value*2^32 in low 48 bits
__device__ __forceinline__ unsigned long long fxpack(float v){
  return CNT1 + (unsigned long long)((double)v * 4294967296.0);
}

__global__ void __launch_bounds__(NTHR, 1)
ntm_kernel(Params P)
{
  const int b   = blockIdx.x;
  const int tid = threadIdx.x;
  const int wv  = tid >> 6;   // wave 0..7
  const int ln  = tid & 63;

  // ------- inputs (setup_inputs dict order) -------
  const float* inputs  = P.in[0];
  const float* mem0    = P.in[1];
  const float* read_w0 = P.in[2];
  const float* write_w0= P.in[3];
  const float* W_ih = P.in[4];
  const float* W_hh = P.in[5];
  const float* b_ih = P.in[6];
  const float* b_hh = P.in[7];
  const float* Wo   = P.in[8];
  const float* bo   = P.in[9];
  const float* r_Wk = P.in[10]; const float* r_bk = P.in[11];
  const float* r_Wb = P.in[12]; const float* r_bb = P.in[13];
  const float* r_Wg = P.in[14]; const float* r_bg = P.in[15];
  const float* r_Ws = P.in[16]; const float* r_bs = P.in[17];
  const float* r_Wp = P.in[18]; const float* r_bp = P.in[19];
  const float* w_Wk = P.in[20]; const float* w_bk = P.in[21];
  const float* w_Wb = P.in[22]; const float* w_bb = P.in[23];
  const float* w_Wg = P.in[24]; const float* w_bg = P.in[25];
  const float* w_Ws = P.in[26]; const float* w_bs = P.in[27];
  const float* w_Wp = P.in[28]; const float* w_bp = P.in[29];
  const float* w_We = P.in[30]; const float* w_be = P.in[31];
  const float* w_Wa = P.in[32]; const float* w_ba = P.in[33];
  float* out = P.out;

  // ------- global scratch layout (ws zeroed at reset) -------
  float* ws = P.ws;
  float* PA = ws;                    // 4096 (rvec partials, 16 groups)
  float* PB = ws + 4096;             // 4096
  unsigned long long* U = (unsigned long long*)(ws + 8192);
  unsigned long long* hpub = U;          // 1024 (128 blocks x 8, tagged h words)
  unsigned long long* ppub = U + 1024;   // 1296 tagged projection slots
  unsigned long long* wEF  = U + 2320;   // boundary words, 128 each
  unsigned long long* wPF  = wEF + 128;
  unsigned long long* wEL  = wPF + 128;
  unsigned long long* wPL  = wEL + 128;
  unsigned long long* rEF  = wPL + 128;
  unsigned long long* rPF  = rEF + 128;
  unsigned long long* rEL  = rPF + 128;
  unsigned long long* rPL  = rEL + 128;
  // 8-way spread reduce slots: redX[slot][t], slot stride = Tlen (1KiB lines)
  unsigned long long* redD = U + 3344;          // 8*Tlen = 1024
  unsigned long long* redF = redD + 8 * Tlen;
  unsigned long long* redH = redF + 8 * Tlen;
  unsigned long long* redJ = redH + 8 * Tlen;
  unsigned long long* redI = redJ + 8 * Tlen;   // 2 init slots
  unsigned long long* redK  = redI + 2;         // Tlen ||keyw||^2 (256 arrivals)
  unsigned long long* redKr = redK + Tlen;      // Tlen ||keyr||^2 (256 arrivals)
  unsigned long long* hcnt  = redKr + Tlen;     // Tlen h-arrival counters
  unsigned long long* pcnt0 = hcnt + Tlen;      // Tlen C-batch0 counters
  unsigned long long* pcnt1 = pcnt0 + Tlen;     // Tlen C-batch1 counters
  float* Pbuf[2] = { PA, PB };
  const int slot = b & 7;

  // ------- LDS -------
  __shared__ float s_mem[RPB * Dsz];   // 128KB
  __shared__ float s_co[Hsz];
  __shared__ float s_a[256];
  __shared__ float s_er[256], s_ad[256], s_kr[256];
  __shared__ float s_rv[256];
  __shared__ float s_norm[RPB];
  __shared__ float s_e[RPB];
  __shared__ float s_bw[RPB];
  __shared__ float s_rw[RPB];
  __shared__ float s_ww[RPB];
  __shared__ float s_A1[RPB], s_A2[RPB], s_B1[RPB], s_B0[RPB];
  __shared__ float s_dot[RPB];
  __shared__ float s_lg[16];
  __shared__ float s_scal[16];
  __shared__ float s_w2[2];
  __shared__ float s_cst[4];
  __shared__ float s_bd[4];
  __shared__ float s_pub;
  __shared__ float s_gval;

  // tid0 polls one count line to target, then block barrier (throttle only;
  // value correctness still carried by tags).
  auto cntGate = [&](unsigned long long* p, unsigned long long target){
    if (tid == 0){
      while (gload64(p) < target) {}
    }
    lbar();
  };

  // 8-slot reduce wait: tid0 polls 8 spread lines until total count==128,
  // sums fixed-point payloads (integer adds -> bit-identical to 1-word sum).
  auto redWait8 = [&](unsigned long long* base, int t)->float{
    if (tid == 0){
      unsigned long long k0,k1,k2,k3,k4,k5,k6,k7;
      for (;;){
        k0 = gload64(base + 0*Tlen + t); k1 = gload64(base + 1*Tlen + t);
        k2 = gload64(base + 2*Tlen + t); k3 = gload64(base + 3*Tlen + t);
        k4 = gload64(base + 4*Tlen + t); k5 = gload64(base + 5*Tlen + t);
        k6 = gload64(base + 6*Tlen + t); k7 = gload64(base + 7*Tlen + t);
        unsigned c = (unsigned)(k0>>48) + (unsigned)(k1>>48)
                   + (unsigned)(k2>>48) + (unsigned)(k3>>48)
                   + (unsigned)(k4>>48) + (unsigned)(k5>>48)
                   + (unsigned)(k6>>48) + (unsigned)(k7>>48);
        if (c >= (unsigned)NBLK) break;
      }
      const unsigned long long m = 0xFFFFFFFFFFFFull;
      unsigned long long s = (k0&m)+(k1&m)+(k2&m)+(k3&m)+(k4&m)+(k5&m)+(k6&m)+(k7&m);
      s_gval = (float)((double)s * (1.0 / 4294967296.0));
    }
    lbar();
    return s_gval;
  };
  // single-word wait with arbitrary arrival target
  auto redWaitC = [&](unsigned long long* p, unsigned target)->float{
    if (tid == 0){
      unsigned long long k;
      do { k = gload64(p); } while ((unsigned)(k >> 48) < target);
      s_gval = (float)((double)(k & 0xFFFFFFFFFFFFull) * (1.0 / 4294967296.0));
    }
    lbar();
    return s_gval;
  };

  // shift + sharpen; boundaries from s_bd; partial -> s_pub (+ fx-publish if slotp)
  auto shiftSharpen = [&](int si, float* s_prevw, float S, unsigned long long* slotp){
    float g     = sigm(s_scal[si + 1]);
    float gamma = softplusf(s_scal[si + 2]) + 1.f;
    float a0 = s_scal[si + 3], a1 = s_scal[si + 4], a2 = s_scal[si + 5];
    float mx = fmaxf(a0, fmaxf(a1, a2));
    float e0 = __expf(a0 - mx), e1 = __expf(a1 - mx), e2 = __expf(a2 - mx);
    float idn = 1.f / (e0 + e1 + e2);
    float s0 = e0 * idn, s1 = e1 * idn, s2 = e2 * idn;
    float invS = 1.f / S;
    float w = 0.f;
    if (tid < RPB){
      float gc = g * invS, gp = 1.f - g;
      float em = s_e[tid],  pm = s_prevw[tid];
      float e1n = (tid < RPB-1) ? s_e[tid+1]     : s_bd[0];
      float p1n = (tid < RPB-1) ? s_prevw[tid+1] : s_bd[1];
      float e2n = (tid > 0)     ? s_e[tid-1]     : s_bd[2];
      float p2n = (tid > 0)     ? s_prevw[tid-1] : s_bd[3];
      float gwm = gc * em  + gp * pm;
      float gw1 = gc * e1n + gp * p1n;   // roll(gw,-1)
      float gw2 = gc * e2n + gp * p2n;   // roll(gw,+1)
      float sh = s0 * gw1 + s1 * gwm + s2 * gw2;
      w = powf(sh, gamma);
      s_bw[tid] = w;
    }
    float tot = wred64(w);
    if (ln == 0 && wv < 2) s_w2[wv] = tot;
    lbar();
    if (tid == 0){
      float T2 = s_w2[0] + s_w2[1];
      s_pub = T2;
      if (slotp) atomicAdd(slotp, fxpack(T2));
    }
  };

  // x-part of this block's 16 gate rows (x read from global)
  auto xpart = [&](const float* xn)->float{
    int dd = tid >> 5, l = tid & 31;
    int r = (dd >> 2) * Hsz + (b << 2) + (dd & 3);
    const float* wi = W_ih + (size_t)r * (Isz + Dsz);
    float acc = 0.f;
#pragma unroll
    for (int it = 0; it < 2; ++it){
      int k = it * 128 + l * 4;
      float4 a = *(const float4*)(wi + k);
      float4 x = *(const float4*)(xn + k);
      acc += a.x*x.x + a.y*x.y + a.z*x.z + a.w*x.w;
    }
    return acc;
  };
  // W_hh . h partial (iters [i0,i1) of 4; h in s_co)
  auto gemvHpart = [&](int i0, int i1)->float{
    int dd = tid >> 5, l = tid & 31;
    int r = (dd >> 2) * Hsz + (b << 2) + (dd & 3);
    const float* wh = W_hh + (size_t)r * Hsz;
    float acc = 0.f;
    for (int it = i0; it < i1; ++it){
      int k = it * 128 + l * 4;
      float4 hw = *(const float4*)(wh + k);
      float4 hv = *(const float4*)(&s_co[k]);
      acc += hw.x*hv.x + hw.y*hv.y + hw.z*hv.z + hw.w*hv.w;
    }
    return acc;
  };

  // one C-phase projection dot for task q (or -1); publishes tagged slot word
  auto projDot = [&](int q, int t, const unsigned long long tg){
    if (q < 0) return;
    int pslot = q * 128 + b;
    if (pslot >= 1292) return;
    const float* Wrow = nullptr; float bias = 0.f; int len = 512;
    int mode = 0;  // 0: tagged pub, 1: sigmoid + pub, 2: out store
    if (pslot < 256){ Wrow = w_Wk + (size_t)pslot * Hsz; bias = w_bk[pslot]; }
    else if (pslot < 512){ int i = pslot - 256; Wrow = w_We + (size_t)i * Hsz; bias = w_be[i]; mode = 1; }
    else if (pslot < 768){ int i = pslot - 512; Wrow = w_Wa + (size_t)i * Hsz; bias = w_ba[i]; }
    else if (pslot < 1024){ int i = pslot - 768; Wrow = r_Wk + (size_t)i * Hsz; bias = r_bk[i]; }
    else if (pslot < 1280){ int i = pslot - 1024; Wrow = Wo + (size_t)i * (Hsz + Dsz); bias = bo[i]; len = 768; mode = 2; }
    else {
      int i = pslot - 1280;
      int ii = (i >= 6) ? i - 6 : i;
      bool rh = (i >= 6);
      const float *Wt, *bt; int row = 0;
      if (ii == 0){ Wt = rh ? r_Wb : w_Wb; bt = rh ? r_bb : w_bb; }
      else if (ii == 1){ Wt = rh ? r_Wg : w_Wg; bt = rh ? r_bg : w_bg; }
      else if (ii == 2){ Wt = rh ? r_Wp : w_Wp; bt = rh ? r_bp : w_bp; }
      else { Wt = rh ? r_Ws : w_Ws; bt = rh ? r_bs : w_bs; row = ii - 3; }
      Wrow = Wt + (size_t)row * Hsz; bias = bt[row];
    }
    float acc = 0.f;
    if (len == 512){
      int k = ln * 8;
      float4 a0 = *(const float4*)(Wrow + k);
      float4 a1 = *(const float4*)(Wrow + k + 4);
      float4 c0 = *(const float4*)(&s_co[k]);
      float4 c1 = *(const float4*)(&s_co[k + 4]);
      acc = a0.x*c0.x + a0.y*c0.y + a0.z*c0.z + a0.w*c0.w
          + a1.x*c1.x + a1.y*c1.y + a1.z*c1.z + a1.w*c1.w;
    } else {
      int k = ln * 4;
      float4 w0 = *(const float4*)(Wrow + k);
      float4 w1 = *(const float4*)(Wrow + 256 + k);
      float4 w2 = *(const float4*)(Wrow + 512 + k);
      float4 c0 = *(const float4*)(&s_co[k]);
      float4 c1 = *(const float4*)(&s_co[256 + k]);
      float4 r0 = *(const float4*)(&s_rv[k]);
      acc = w0.x*c0.x + w0.y*c0.y + w0.z*c0.z + w0.w*c0.w
          + w1.x*c1.x + w1.y*c1.y + w1.z*c1.z + w1.w*c1.w
          + w2.x*r0.x + w2.y*r0.y + w2.z*r0.z + w2.w*r0.w;
    }
    acc = wred64(acc);
    if (ln == 0){
      float v = acc + bias;
      if (mode == 1) v = sigm(v);
      if (mode == 2) out[(size_t)t * Isz + (pslot - 1024)] = v;
      else gstore64(&ppub[pslot], tg | (unsigned long long)__float_as_uint(v));
      if (q <= 1)                 atomicAdd(redK  + t, fxpack(v * v));  // keyw
      else if (q == 6 || q == 7)  atomicAdd(redKr + t, fxpack(v * v));  // keyr
    }
  };

  float Srcarry = 1.f;
  float accxh = 0.f, accX = 0.f, accH = 0.f;

  // ------- INIT1: zero parts; load initial state -------
  {
    if (b < NG && tid < 256){ gstore(&PA[b*256 + tid], 0.f); gstore(&PB[b*256 + tid], 0.f); }
    if (tid < RPB){
      s_rw[tid] = read_w0[b * RPB + tid];
      s_ww[tid] = write_w0[b * RPB + tid];
    }
    if (tid < 4) s_cst[tid] = 0.f;
    s_co[tid] = 0.f;
    __syncthreads();                               // drain zero stores
    if (tid == 0) atomicAdd(redI + 0, CNT1);
    redWaitC(redI + 0, NBLK);
  }

  // ------- INIT2: memory -> LDS, norms, initial rvec partials -------
  {
#pragma unroll 1
    for (int it = 0; it < 16; ++it){
      int ml = it * 8 + wv;
      int m  = b * RPB + ml;
      float4 v = *(const float4*)(mem0 + (size_t)m * Dsz + ln * 4);
      *(float4*)(&s_mem[ml * Dsz + ln * 4]) = v;
      float n2 = wred64(v.x*v.x + v.y*v.y + v.z*v.z + v.w*v.w);
      if (ln == 0) s_norm[ml] = sqrtf(n2);
    }
    lbar();
    int col = tid & 255, half = tid >> 8;
    float acc = 0.f;
#pragma unroll 1
    for (int j = half * 64; j < half * 64 + 64; ++j) acc += s_rw[j] * s_mem[j * Dsz + col];
    if (half == 0) s_a[col] = acc;
    lbar();
    if (half == 1) atomicAdd(&PB[(b & (NG-1)) * 256 + col], acc + s_a[col]);
    __syncthreads();                               // drain atomics
    if (tid == 0) atomicAdd(redI + 1, CNT1);
    accxh = xpart(inputs);                         // gates(0): h(-1)=0
    redWaitC(redI + 1, NBLK);
  }

  // =================== time loop ===================
  for (int t = 0; t < Tlen; ++t){
    const unsigned TT = (unsigned)(t + 3);
    const unsigned long long tg = (unsigned long long)TT << 32;
    float* Pcur = Pbuf[t & 1];          // J(t) atomics
    float* Prd  = Pbuf[(t + 1) & 1];    // A(t) reads

    // ---- A: deferred rw/rvec normalize; finish LSTM; publish tagged h ----
    {
      float SrDiv = (t == 0) ? 1.f : (Srcarry + 1e-8f);
      if (t > 0 && tid < RPB) s_rw[tid] = s_bw[tid] / SrDiv;
      if (tid < 256){
        float rvv = 0.f;
#pragma unroll
        for (int p = 0; p < NG; ++p) rvv += gload(&Prd[p * 256 + tid]);
        s_rv[tid] = rvv / SrDiv;
      }
      lbar();
      int dd = tid >> 5, l = tid & 31;
      int r = (dd >> 2) * Hsz + (b << 2) + (dd & 3);
      const float* wi = W_ih + (size_t)r * (Isz + Dsz) + Isz;
      float acc = accxh;
#pragma unroll
      for (int it = 0; it < 2; ++it){
        int k = it * 128 + l * 4;
        float4 a = *(const float4*)(wi + k);
        float4 x = *(const float4*)(&s_rv[k]);
        acc += a.x*x.x + a.y*x.y + a.z*x.z + a.w*x.w;
      }
      acc = wred32(acc);
      if (l == 0) s_lg[dd] = acc + b_ih[r] + b_hh[r];
      lbar();
      if (tid < 4){
        float iv = s_lg[tid], fv = s_lg[4 + tid], gv = s_lg[8 + tid], ov = s_lg[12 + tid];
        float cn = sigm(fv) * s_cst[tid] + sigm(iv) * tanhf(gv);
        s_cst[tid] = cn;
        float hn = sigm(ov) * tanhf(cn);
        gstore64(&hpub[(size_t)b * 8 + tid], tg | (unsigned long long)__float_as_uint(hn));
      }
      lbar();
      if (tid == 0) atomicAdd(hcnt + t, 1ull);   // arrival count (throttle)
    }

    // ---- C: count-gated h read; projections batch0 (+count) / batch1 ----
    {
      cntGate(hcnt + t, NBLK);
      s_co[tid] = pollw(&hpub[(size_t)(tid >> 2) * 8 + (tid & 3)], TT);  // ~1 iter
      lbar();
      // batch0: everything D/F/H need (keyw q0,1; scal q10; er q2,3; ad q4,5; kr q6)
      const int QB0[8] = {0,1,10,2,3,4,5,6};
      const int QB1[8] = {7,8,9,-1,-1,-1,-1,-1};
      projDot(QB0[wv], t, tg);
      lbar();
      if (tid == 0) atomicAdd(pcnt0 + t, 1ull);
      // batch1: kr second half (q7), Wo out dots (q8,9)
      projDot(QB1[wv], t, tg);
      lbar();
      if (tid == 0) atomicAdd(pcnt1 + t, 1ull);
    }

    if (t == Tlen - 1) break;   // out(127) done; D..J only produce next-step state

    float betaR = 0.f, invbkR = 0.f;

    // ---- D: x-part prefetch; count-gated keyw+scal; content scores ----
    {
      accX = xpart(inputs + (size_t)(t + 1) * Isz);
      float* Pnx = Pbuf[(t + 1) & 1];
      // safe: C's hcnt gate proves all blocks are past A(t)'s Prd reads
      if (b < NG && tid < 256) gstore(&Pnx[b * 256 + tid], 0.f);
      cntGate(pcnt0 + t, NBLK);
      if (tid < 256) s_a[tid] = pollw(&ppub[tid], TT);                 // ~1 iter
      else if (tid < 268) s_scal[tid - 256] = pollw(&ppub[1280 + (tid - 256)], TT);
      float nk2 = redWaitC(redK + t, 256);     // lbar orders s_a/s_scal too
      float beta  = softplusf(s_scal[0]);
      float invbk = beta / fmaxf(sqrtf(nk2), 1e-12f);
      int row = tid >> 2, q = tid & 3;
      const float* mrow = &s_mem[row * Dsz];
      float d = 0.f;
#pragma unroll
      for (int k = 0; k < 16; ++k){
        int c = (q + 4 * ((k + row) & 15)) * 4;   // rotated chunk: bank spread
        float4 mv = *(const float4*)(mrow + c);
        float4 kv = *(const float4*)(&s_a[c]);
        d += mv.x*kv.x + mv.y*kv.y + mv.z*kv.z + mv.w*kv.w;
      }
      d = qsum4(d);
      if (q == 0) s_dot[row] = d;
      lbar();
      float e = 0.f;
      if (tid < RPB){
        float score = s_dot[tid] * invbk / fmaxf(s_norm[tid], 1e-12f);
        e = __expf(score - beta);
        s_e[tid] = e;
      }
      float tot = wred64(e);
      if (ln == 0 && wv < 2) s_w2[wv] = tot;
      lbar();
      if (tid == 0){
        float T = s_w2[0] + s_w2[1];
        gstore64(&wEF[b], tg | (unsigned long long)__float_as_uint(s_e[0]));
        gstore64(&wPF[b], tg | (unsigned long long)__float_as_uint(s_ww[0]));
        gstore64(&wEL[b], tg | (unsigned long long)__float_as_uint(s_e[RPB-1]));
        gstore64(&wPL[b], tg | (unsigned long long)__float_as_uint(s_ww[RPB-1]));
        atomicAdd(redD + slot * Tlen + t, fxpack(T));
      }
    }

    // ---- H-pre: count-gated er/ad/kr; Sw-independent reductions ----
    {
      cntGate(pcnt1 + t, NBLK);
      if (tid < 256) s_er[tid] = pollw(&ppub[256 + tid], TT);          // ~1 iter
      else           s_ad[tid - 256] = pollw(&ppub[512 + (tid - 256)], TT);
      if (tid < 256) s_kr[tid] = pollw(&ppub[768 + tid], TT);
      float nk2r = redWaitC(redKr + t, 256);   // lbar orders s_er/s_ad/s_kr
      betaR  = softplusf(s_scal[6]);
      invbkR = betaR / fmaxf(sqrtf(nk2r), 1e-12f);
      int row = tid >> 2, q = tid & 3;
      const float* mrow = &s_mem[row * Dsz];
      float mq = 0.f, qq = 0.f, qk = 0.f, mk = 0.f;
#pragma unroll
      for (int k = 0; k < 16; ++k){
        int c = (q + 4 * ((k + row) & 15)) * 4;
        float4 mv = *(const float4*)(mrow + c);
        float4 er = *(const float4*)(&s_er[c]);
        float4 ad = *(const float4*)(&s_ad[c]);
        float4 kr = *(const float4*)(&s_kr[c]);
        float qx = ad.x - mv.x * er.x;
        float qy = ad.y - mv.y * er.y;
        float qz = ad.z - mv.z * er.z;
        float qw = ad.w - mv.w * er.w;
        mq += mv.x*qx + mv.y*qy + mv.z*qz + mv.w*qw;
        qq += qx*qx + qy*qy + qz*qz + qw*qw;
        qk += qx*kr.x + qy*kr.y + qz*kr.z + qw*kr.w;
        mk += mv.x*kr.x + mv.y*kr.y + mv.z*kr.z + mv.w*kr.w;
      }
      mq = qsum4(mq); qq = qsum4(qq); qk = qsum4(qk); mk = qsum4(mk);
      if (q == 0){ s_A1[row] = 2.f*mq; s_A2[row] = qq; s_B1[row] = qk; s_B0[row] = mk; }
    }

    // ---- F: write sharpen; h gather; gemvH half hides redF propagation ----
    {
      if (wv == 0 && ln < 4){
        const unsigned long long* bp = (ln == 0) ? &wEF[(b + 1) & (NBLK-1)]
                               : (ln == 1) ? &wPF[(b + 1) & (NBLK-1)]
                               : (ln == 2) ? &wEL[(b - 1) & (NBLK-1)]
                                           : &wPL[(b - 1) & (NBLK-1)];
        s_bd[ln] = pollw(bp, TT);
      }
      float S_w = redWait8(redD, t);
      shiftSharpen(0, s_ww, S_w, redF + slot * Tlen + t);
      s_co[tid] = pollw(&hpub[(size_t)(tid >> 2) * 8 + (tid & 3)], TT);  // h(t), arrived
      lbar();                                   // order s_co before broad reads
      accH = gemvHpart(0, 2);                   // W_hh*h iters 0-1
    }

    // ---- H-post: wait Sw; S_r fixups + publish FIRST, then mem update ----
    {
      float Sw = redWait8(redF, t);
      float invSw = 1.f / (Sw + 1e-8f);
      float4 er4 = *(const float4*)(&s_er[ln * 4]);
      float4 ad4 = *(const float4*)(&s_ad[ln * 4]);
      float e = 0.f;
      if (tid < RPB){
        float wwm = s_bw[tid] * invSw;
        s_ww[tid] = wwm;
        float A0 = s_norm[tid] * s_norm[tid];
        float n2 = fmaf(wwm, fmaf(wwm, s_A2[tid], s_A1[tid]), A0);
        float dt = fmaf(wwm, s_B1[tid], s_B0[tid]);
        float nr = sqrtf(fmaxf(n2, 0.f));
        s_norm[tid] = nr;
        float score = dt * invbkR / fmaxf(nr, 1e-12f);
        e = __expf(score - betaR);
        s_e[tid] = e;
      }
      float tot = wred64(e);
      if (ln == 0 && wv < 2) s_w2[wv] = tot;
      lbar();
      if (tid == 0){
        float T2 = s_w2[0] + s_w2[1];
        gstore64(&rEF[b], tg | (unsigned long long)__float_as_uint(s_e[0]));
        gstore64(&rPF[b], tg | (unsigned long long)__float_as_uint(s_rw[0]));
        gstore64(&rEL[b], tg | (unsigned long long)__float_as_uint(s_e[RPB-1]));
        gstore64(&rPL[b], tg | (unsigned long long)__float_as_uint(s_rw[RPB-1]));
        atomicAdd(redH + slot * Tlen + t, fxpack(T2));
      }
      // mem update runs while S_r propagates
#pragma unroll 1
      for (int it = 0; it < 16; ++it){
        int ml = it * 8 + wv;
        int off = ml * Dsz + ln * 4;
        float wwm = s_bw[ml] * invSw;
        float4 mv = *(const float4*)(&s_mem[off]);
        float4 nv;
        nv.x = fmaf(wwm, ad4.x - mv.x * er4.x, mv.x);
        nv.y = fmaf(wwm, ad4.y - mv.y * er4.y, mv.y);
        nv.z = fmaf(wwm, ad4.z - mv.z * er4.z, mv.z);
        nv.w = fmaf(wwm, ad4.w - mv.w * er4.w, mv.w);
        *(float4*)(&s_mem[off]) = nv;
      }
    }

    // ---- J: read sharpen; rvec partials; gemvH tail hides redJ wait ----
    {
      if (wv == 0 && ln < 4){
        const unsigned long long* bp = (ln == 0) ? &rEF[(b + 1) & (NBLK-1)]
                               : (ln == 1) ? &rPF[(b + 1) & (NBLK-1)]
                               : (ln == 2) ? &rEL[(b - 1) & (NBLK-1)]
                                           : &rPL[(b - 1) & (NBLK-1)];
        s_bd[ln] = pollw(bp, TT);
      }
      float S_r = redWait8(redH, t);
      shiftSharpen(6, s_rw, S_r, nullptr);   // partial left in s_pub
      lbar();
      int col = tid & 255, half = tid >> 8;
      float acc = 0.f;
#pragma unroll 1
      for (int j = half * 64; j < half * 64 + 64; ++j) acc += s_bw[j] * s_mem[j * Dsz + col];
      if (half == 0) s_a[col] = acc;
      lbar();
      if (half == 1) atomicAdd(&Pcur[(b & (NG-1)) * 256 + col], acc + s_a[col]);
      __syncthreads();                       // drain atomics before publish
      if (tid == 0) atomicAdd(redJ + slot * Tlen + t, fxpack(s_pub));
      accxh = accX + accH + gemvHpart(2, 4); // finish gates(t+1) x+hh parts
      Srcarry = redWait8(redJ, t);
    }
  }
}

extern "C" void kernel_launch(void* const* d_in, const int* in_sizes, int n_in,
                              void* d_out, int out_size, void* d_ws, size_t ws_size,
                              hipStream_t stream)
{
  (void)in_sizes; (void)out_size;
  if (n_in < 34) return;
  if (ws_size < (size_t)98304) return;
  Params P;
  for (int i = 0; i < 34; ++i) P.in[i] = (const float*)d_in[i];
  P.out = (float*)d_out;
  P.ws  = (float*)d_ws;
  hipLaunchKernelGGL(ntm_kernel, dim3(NBLK), dim3(NTHR), 0, stream, P);
}

// Round 12
// 3590.163 us; speedup vs baseline: 1.0247x; 1.0247x over previous
//
#include <hip/hip_runtime.h>
#include <math.h>

// Persistent-kernel NTM, R23 = R19 (session champion, verified: dispatches
// 3518-3532us, absmax 0.0039). Final revert after the one-hop projection
// topology (R15-R18, R22) was retired: two independent builds produced a
// bit-identical deterministic failure (absmax 5603328.47) under different
// layouts -> systematic derivation error, unlocated in 5 audits.
// Ledger: R13 quad-per-row DPP reductions = -28%; all six sync-plumbing
// variants (R14/R19/R20/R21 mechanisms) = null +/-1%. Remaining ~27.5us/step
// = 5-deep global scalar dependency chain x ~3.3us device-scope hop latency
// (invariant to publish/poll/atomic mechanics) + ~11us compute.

#define NBLK 128
#define NTHR 512
#define Msz  16384
#define Dsz  256
#define Hsz  512
#define Isz  256
#define Tlen 128
#define RPB  128
#define NG   16

#define CNT1 (1ull << 48)

struct Params { const float* in[34]; float* out; float* ws; };

__device__ __forceinline__ float wred64(float v){
#pragma unroll
  for (int o = 32; o > 0; o >>= 1) v += __shfl_xor(v, o, 64);
  return v;
}
__device__ __forceinline__ float wred32(float v){
#pragma unroll
  for (int o = 16; o > 0; o >>= 1) v += __shfl_xor(v, o, 32);
  return v;
}
// sum over each 4-lane quad via DPP quad_perm (no DS ops, no bank conflicts)
__device__ __forceinline__ float qsum4(float v){
  v += __uint_as_float(__builtin_amdgcn_mov_dpp(__float_as_uint(v), 0xB1, 0xF, 0xF, true)); // xor1
  v += __uint_as_float(__builtin_amdgcn_mov_dpp(__float_as_uint(v), 0x4E, 0xF, 0xF, true)); // xor2
  return v;
}
__device__ __forceinline__ float sigm(float x){ return 1.f / (1.f + __expf(-x)); }
__device__ __forceinline__ float softplusf(float x){ return (x > 20.f) ? x : log1pf(__expf(x)); }

__device__ __forceinline__ void gstore(float* p, float v){
  __hip_atomic_store(p, v, __ATOMIC_RELAXED, __HIP_MEMORY_SCOPE_AGENT);
}
__device__ __forceinline__ float gload(const float* p){
  return __hip_atomic_load(p, __ATOMIC_RELAXED, __HIP_MEMORY_SCOPE_AGENT);
}
__device__ __forceinline__ void gstore64(unsigned long long* p, unsigned long long v){
  __hip_atomic_store(p, v, __ATOMIC_RELAXED, __HIP_MEMORY_SCOPE_AGENT);
}
__device__ __forceinline__ unsigned long long gload64(const unsigned long long* p){
  return __hip_atomic_load(p, __ATOMIC_RELAXED, __HIP_MEMORY_SCOPE_AGENT);
}
// lgkmcnt(0)-only barrier: vmcnt=63, expcnt=7, lgkmcnt=0 -> imm 0xC07F
__device__ __forceinline__ void lbar(){
  __builtin_amdgcn_s_waitcnt(0xC07F);
  __builtin_amdgcn_s_barrier();
}
// poll a tagged word until tag >= want; return payload float
__device__ __forceinline__ float pollw(const unsigned long long* p, unsigned want){
  unsigned long long k;
  do { k = gload64(p); } while ((int)((unsigned)(k >> 32) - want) < 0);
  return __uint_as_float((unsigned)k);
}
// fixed-point publish word: count 1 in bits 48+, value*2^32 in low 48 bits
__device__ __forceinline__ unsigned long long fxpack(float v){
  return CNT1 + (unsigned long long)((double)v * 4294967296.0);
}

__global__ void __launch_bounds__(NTHR, 1)
ntm_kernel(Params P)
{
  const int b   = blockIdx.x;
  const int tid = threadIdx.x;
  const int wv  = tid >> 6;   // wave 0..7
  const int ln  = tid & 63;

  // ------- inputs (setup_inputs dict order) -------
  const float* inputs  = P.in[0];
  const float* mem0    = P.in[1];
  const float* read_w0 = P.in[2];
  const float* write_w0= P.in[3];
  const float* W_ih = P.in[4];
  const float* W_hh = P.in[5];
  const float* b_ih = P.in[6];
  const float* b_hh = P.in[7];
  const float* Wo   = P.in[8];
  const float* bo   = P.in[9];
  const float* r_Wk = P.in[10]; const float* r_bk = P.in[11];
  const float* r_Wb = P.in[12]; const float* r_bb = P.in[13];
  const float* r_Wg = P.in[14]; const float* r_bg = P.in[15];
  const float* r_Ws = P.in[16]; const float* r_bs = P.in[17];
  const float* r_Wp = P.in[18]; const float* r_bp = P.in[19];
  const float* w_Wk = P.in[20]; const float* w_bk = P.in[21];
  const float* w_Wb = P.in[22]; const float* w_bb = P.in[23];
  const float* w_Wg = P.in[24]; const float* w_bg = P.in[25];
  const float* w_Ws = P.in[26]; const float* w_bs = P.in[27];
  const float* w_Wp = P.in[28]; const float* w_bp = P.in[29];
  const float* w_We = P.in[30]; const float* w_be = P.in[31];
  const float* w_Wa = P.in[32]; const float* w_ba = P.in[33];
  float* out = P.out;

  // ------- global scratch layout (ws zeroed at reset) -------
  float* ws = P.ws;
  float* PA = ws;                    // 4096 (rvec partials, 16 groups)
  float* PB = ws + 4096;             // 4096
  unsigned long long* U = (unsigned long long*)(ws + 8192);
  unsigned long long* hpub = U;          // 1024 (128 blocks x 8, tagged h words)
  unsigned long long* ppub = U + 1024;   // 1296 tagged projection slots
  unsigned long long* wEF  = U + 2320;   // boundary words, 128 each
  unsigned long long* wPF  = wEF + 128;
  unsigned long long* wEL  = wPF + 128;
  unsigned long long* wPL  = wEL + 128;
  unsigned long long* rEF  = wPL + 128;
  unsigned long long* rPF  = rEF + 128;
  unsigned long long* rEL  = rPF + 128;
  unsigned long long* rPL  = rEL + 128;
  // 8-way spread reduce slots: redX[slot][t], slot stride = Tlen (1KiB lines)
  unsigned long long* redD = U + 3344;          // 8*Tlen = 1024
  unsigned long long* redF = redD + 8 * Tlen;
  unsigned long long* redH = redF + 8 * Tlen;
  unsigned long long* redJ = redH + 8 * Tlen;
  unsigned long long* redI = redJ + 8 * Tlen;   // 2 init slots (single-word)
  float* Pbuf[2] = { PA, PB };
  const int slot = b & 7;

  // ------- LDS -------
  __shared__ float s_mem[RPB * Dsz];   // 128KB
  __shared__ float s_co[Hsz];
  __shared__ float s_a[256];
  __shared__ float s_er[256], s_ad[256], s_kr[256];
  __shared__ float s_rv[256];
  __shared__ float s_norm[RPB];
  __shared__ float s_e[RPB];
  __shared__ float s_bw[RPB];
  __shared__ float s_rw[RPB];
  __shared__ float s_ww[RPB];
  __shared__ float s_A1[RPB], s_A2[RPB], s_B1[RPB], s_B0[RPB];
  __shared__ float s_dot[RPB];
  __shared__ float s_red[8];
  __shared__ float s_lg[16];
  __shared__ float s_scal[16];
  __shared__ float s_w2[2];
  __shared__ float s_cst[4];
  __shared__ float s_bd[4];
  __shared__ float s_pub;
  __shared__ float s_gval;

  // 8-slot reduce wait: tid0 polls 8 spread lines until total count==128,
  // sums fixed-point payloads (integer adds -> bit-identical to 1-word sum).
  auto redWait8 = [&](unsigned long long* base, int t)->float{
    if (tid == 0){
      unsigned long long k0,k1,k2,k3,k4,k5,k6,k7;
      for (;;){
        k0 = gload64(base + 0*Tlen + t); k1 = gload64(base + 1*Tlen + t);
        k2 = gload64(base + 2*Tlen + t); k3 = gload64(base + 3*Tlen + t);
        k4 = gload64(base + 4*Tlen + t); k5 = gload64(base + 5*Tlen + t);
        k6 = gload64(base + 6*Tlen + t); k7 = gload64(base + 7*Tlen + t);
        unsigned c = (unsigned)(k0>>48) + (unsigned)(k1>>48)
                   + (unsigned)(k2>>48) + (unsigned)(k3>>48)
                   + (unsigned)(k4>>48) + (unsigned)(k5>>48)
                   + (unsigned)(k6>>48) + (unsigned)(k7>>48);
        if (c >= (unsigned)NBLK) break;
      }
      const unsigned long long m = 0xFFFFFFFFFFFFull;
      unsigned long long s = (k0&m)+(k1&m)+(k2&m)+(k3&m)+(k4&m)+(k5&m)+(k6&m)+(k7&m);
      s_gval = (float)((double)s * (1.0 / 4294967296.0));
    }
    lbar();
    return s_gval;
  };
  // single-word wait (init only)
  auto redWait1 = [&](unsigned long long* p)->float{
    if (tid == 0){
      unsigned long long k;
      do { k = gload64(p); } while ((unsigned)(k >> 48) < (unsigned)NBLK);
      s_gval = (float)((double)(k & 0xFFFFFFFFFFFFull) * (1.0 / 4294967296.0));
    }
    lbar();
    return s_gval;
  };

  auto bred512 = [&](float v)->float{
    v = wred64(v);
    lbar();
    if (ln == 0) s_red[wv] = v;
    lbar();
    return s_red[0] + s_red[1] + s_red[2] + s_red[3]
         + s_red[4] + s_red[5] + s_red[6] + s_red[7];
  };

  // shift + sharpen; boundaries from s_bd; partial -> s_pub (+ fx-publish if slotp)
  auto shiftSharpen = [&](int si, float* s_prevw, float S, unsigned long long* slotp){
    float g     = sigm(s_scal[si + 1]);
    float gamma = softplusf(s_scal[si + 2]) + 1.f;
    float a0 = s_scal[si + 3], a1 = s_scal[si + 4], a2 = s_scal[si + 5];
    float mx = fmaxf(a0, fmaxf(a1, a2));
    float e0 = __expf(a0 - mx), e1 = __expf(a1 - mx), e2 = __expf(a2 - mx);
    float idn = 1.f / (e0 + e1 + e2);
    float s0 = e0 * idn, s1 = e1 * idn, s2 = e2 * idn;
    float invS = 1.f / S;
    float w = 0.f;
    if (tid < RPB){
      float gc = g * invS, gp = 1.f - g;
      float em = s_e[tid],  pm = s_prevw[tid];
      float e1n = (tid < RPB-1) ? s_e[tid+1]     : s_bd[0];
      float p1n = (tid < RPB-1) ? s_prevw[tid+1] : s_bd[1];
      float e2n = (tid > 0)     ? s_e[tid-1]     : s_bd[2];
      float p2n = (tid > 0)     ? s_prevw[tid-1] : s_bd[3];
      float gwm = gc * em  + gp * pm;
      float gw1 = gc * e1n + gp * p1n;   // roll(gw,-1)
      float gw2 = gc * e2n + gp * p2n;   // roll(gw,+1)
      float sh = s0 * gw1 + s1 * gwm + s2 * gw2;
      w = powf(sh, gamma);
      s_bw[tid] = w;
    }
    float tot = wred64(w);
    if (ln == 0 && wv < 2) s_w2[wv] = tot;
    lbar();
    if (tid == 0){
      float T2 = s_w2[0] + s_w2[1];
      s_pub = T2;
      if (slotp) atomicAdd(slotp, fxpack(T2));
    }
  };

  // LSTM GEMV, x-part (s_a) + h-part (s_co); rvec part added later in A
  auto gemvXH = [&]()->float{
    int dd = tid >> 5, l = tid & 31;
    int r = (dd >> 2) * Hsz + (b << 2) + (dd & 3);
    const float* wi = W_ih + (size_t)r * (Isz + Dsz);
    const float* wh = W_hh + (size_t)r * Hsz;
    float acc = 0.f;
#pragma unroll
    for (int it = 0; it < 2; ++it){
      int k = it * 128 + l * 4;
      float4 a = *(const float4*)(wi + k);
      float4 x = *(const float4*)(&s_a[k]);
      acc += a.x*x.x + a.y*x.y + a.z*x.z + a.w*x.w;
    }
#pragma unroll
    for (int it = 0; it < 4; ++it){
      int k = it * 128 + l * 4;
      float4 hw = *(const float4*)(wh + k);
      float4 hv = *(const float4*)(&s_co[k]);
      acc += hw.x*hv.x + hw.y*hv.y + hw.z*hv.z + hw.w*hv.w;
    }
    return acc;
  };

  float Srcarry = 1.f;
  float accxh   = 0.f;

  // ------- INIT1: zero parts; load initial state -------
  {
    if (b < NG && tid < 256){ gstore(&PA[b*256 + tid], 0.f); gstore(&PB[b*256 + tid], 0.f); }
    if (tid < RPB){
      s_rw[tid] = read_w0[b * RPB + tid];
      s_ww[tid] = write_w0[b * RPB + tid];
    }
    if (tid < 4) s_cst[tid] = 0.f;
    s_co[tid] = 0.f;
    __syncthreads();                               // drain zero stores
    if (tid == 0) atomicAdd(redI + 0, CNT1);
    redWait1(redI + 0);
  }

  // ------- INIT2: memory -> LDS, norms, initial rvec partials -------
  {
#pragma unroll 1
    for (int it = 0; it < 16; ++it){
      int ml = it * 8 + wv;
      int m  = b * RPB + ml;
      float4 v = *(const float4*)(mem0 + (size_t)m * Dsz + ln * 4);
      *(float4*)(&s_mem[ml * Dsz + ln * 4]) = v;
      float n2 = wred64(v.x*v.x + v.y*v.y + v.z*v.z + v.w*v.w);
      if (ln == 0) s_norm[ml] = sqrtf(n2);
    }
    lbar();
    int col = tid & 255, half = tid >> 8;
    float acc = 0.f;
#pragma unroll 1
    for (int j = half * 64; j < half * 64 + 64; ++j) acc += s_rw[j] * s_mem[j * Dsz + col];
    if (half == 0) s_a[col] = acc;
    lbar();
    if (half == 1) atomicAdd(&PB[(b & (NG-1)) * 256 + col], acc + s_a[col]);
    __syncthreads();                               // drain atomics
    if (tid < 256) s_a[tid] = inputs[tid];         // stage x(0)
    if (tid == 0) atomicAdd(redI + 1, CNT1);
    lbar();
    accxh = gemvXH();                              // h = 0 -> W_hh part is 0
    redWait1(redI + 1);
  }

  // =================== time loop ===================
  for (int t = 0; t < Tlen; ++t){
    const unsigned TT = (unsigned)(t + 3);
    const unsigned long long tg = (unsigned long long)TT << 32;
    float* Pcur = Pbuf[t & 1];          // J(t) atomics
    float* Prd  = Pbuf[(t + 1) & 1];    // A(t) reads

    // ---- A: deferred rw/rvec normalize; finish LSTM; publish tagged h ----
    {
      float SrDiv = (t == 0) ? 1.f : (Srcarry + 1e-8f);
      if (t > 0 && tid < RPB) s_rw[tid] = s_bw[tid] / SrDiv;
      if (tid < 256){
        float rvv = 0.f;
#pragma unroll
        for (int p = 0; p < NG; ++p) rvv += gload(&Prd[p * 256 + tid]);
        s_rv[tid] = rvv / SrDiv;
      }
      lbar();
      int dd = tid >> 5, l = tid & 31;
      int r = (dd >> 2) * Hsz + (b << 2) + (dd & 3);
      const float* wi = W_ih + (size_t)r * (Isz + Dsz) + Isz;
      float acc = accxh;
#pragma unroll
      for (int it = 0; it < 2; ++it){
        int k = it * 128 + l * 4;
        float4 a = *(const float4*)(wi + k);
        float4 x = *(const float4*)(&s_rv[k]);
        acc += a.x*x.x + a.y*x.y + a.z*x.z + a.w*x.w;
      }
      acc = wred32(acc);
      if (l == 0) s_lg[dd] = acc + b_ih[r] + b_hh[r];
      lbar();
      if (tid < 4){
        float iv = s_lg[tid], fv = s_lg[4 + tid], gv = s_lg[8 + tid], ov = s_lg[12 + tid];
        float cn = sigm(fv) * s_cst[tid] + sigm(iv) * tanhf(gv);
        s_cst[tid] = cn;
        float hn = sigm(ov) * tanhf(cn);
        gstore64(&hpub[(size_t)b * 8 + tid], tg | (unsigned long long)__float_as_uint(hn));
      }
    }

    // ---- C: poll tagged h; projections -> tagged slot words / out ----
    {
      s_co[tid] = pollw(&hpub[(size_t)(tid >> 2) * 8 + (tid & 3)], TT);
      lbar();
#pragma unroll
      for (int qi = 0; qi < 2; ++qi){
        int q = qi * 8 + wv;          // 0..15
        int pslot = q * 128 + b;
        if (pslot < 1292){
          const float* Wrow = nullptr; float bias = 0.f; int len = 512;
          int mode = 0;  // 0: tagged pub, 1: sigmoid + pub, 2: out store
          if (pslot < 256){ Wrow = w_Wk + (size_t)pslot * Hsz; bias = w_bk[pslot]; }
          else if (pslot < 512){ int i = pslot - 256; Wrow = w_We + (size_t)i * Hsz; bias = w_be[i]; mode = 1; }
          else if (pslot < 768){ int i = pslot - 512; Wrow = w_Wa + (size_t)i * Hsz; bias = w_ba[i]; }
          else if (pslot < 1024){ int i = pslot - 768; Wrow = r_Wk + (size_t)i * Hsz; bias = r_bk[i]; }
          else if (pslot < 1280){ int i = pslot - 1024; Wrow = Wo + (size_t)i * (Hsz + Dsz); bias = bo[i]; len = 768; mode = 2; }
          else {
            int i = pslot - 1280;
            int ii = (i >= 6) ? i - 6 : i;
            bool rh = (i >= 6);
            const float *Wt, *bt; int row = 0;
            if (ii == 0){ Wt = rh ? r_Wb : w_Wb; bt = rh ? r_bb : w_bb; }
            else if (ii == 1){ Wt = rh ? r_Wg : w_Wg; bt = rh ? r_bg : w_bg; }
            else if (ii == 2){ Wt = rh ? r_Wp : w_Wp; bt = rh ? r_bp : w_bp; }
            else { Wt = rh ? r_Ws : w_Ws; bt = rh ? r_bs : w_bs; row = ii - 3; }
            Wrow = Wt + (size_t)row * Hsz; bias = bt[row];
          }
          float acc = 0.f;
          if (len == 512){
            int k = ln * 8;
            float4 a0 = *(const float4*)(Wrow + k);
            float4 a1 = *(const float4*)(Wrow + k + 4);
            float4 c0 = *(const float4*)(&s_co[k]);
            float4 c1 = *(const float4*)(&s_co[k + 4]);
            acc = a0.x*c0.x + a0.y*c0.y + a0.z*c0.z + a0.w*c0.w
                + a1.x*c1.x + a1.y*c1.y + a1.z*c1.z + a1.w*c1.w;
          } else {
            int k = ln * 4;
            float4 w0 = *(const float4*)(Wrow + k);
            float4 w1 = *(const float4*)(Wrow + 256 + k);
            float4 w2 = *(const float4*)(Wrow + 512 + k);
            float4 c0 = *(const float4*)(&s_co[k]);
            float4 c1 = *(const float4*)(&s_co[256 + k]);
            float4 r0 = *(const float4*)(&s_rv[k]);
            acc = w0.x*c0.x + w0.y*c0.y + w0.z*c0.z + w0.w*c0.w
                + w1.x*c1.x + w1.y*c1.y + w1.z*c1.z + w1.w*c1.w
                + w2.x*r0.x + w2.y*r0.y + w2.z*r0.z + w2.w*r0.w;
          }
          acc = wred64(acc);
          if (ln == 0){
            float v = acc + bias;
            if (mode == 1) v = sigm(v);
            if (mode == 2) out[(size_t)t * Isz + (pslot - 1024)] = v;
            else gstore64(&ppub[pslot], tg | (unsigned long long)__float_as_uint(v));
          }
        }
      }
    }

    if (t == Tlen - 1) break;   // out(127) done; D..J only produce next-step state

    float betaR = 0.f, invbkR = 0.f;

    // ---- D: poll keyw+scal; write-head content scores (quad-per-row, DPP) ----
    {
      float* Pnx = Pbuf[(t + 1) & 1];
      if (b < NG && tid < 256) gstore(&Pnx[b * 256 + tid], 0.f);
      if (tid < 256) s_a[tid] = pollw(&ppub[tid], TT);
      else if (tid < 268) s_scal[tid - 256] = pollw(&ppub[1280 + (tid - 256)], TT);
      lbar();
      float nk2 = bred512((tid < 256) ? s_a[tid] * s_a[tid] : 0.f);
      float beta  = softplusf(s_scal[0]);
      float invbk = beta / fmaxf(sqrtf(nk2), 1e-12f);
      int row = tid >> 2, q = tid & 3;
      const float* mrow = &s_mem[row * Dsz];
      float d = 0.f;
#pragma unroll
      for (int k = 0; k < 16; ++k){
        int c = (q + 4 * ((k + row) & 15)) * 4;   // rotated chunk: bank spread
        float4 mv = *(const float4*)(mrow + c);
        float4 kv = *(const float4*)(&s_a[c]);
        d += mv.x*kv.x + mv.y*kv.y + mv.z*kv.z + mv.w*kv.w;
      }
      d = qsum4(d);
      if (q == 0) s_dot[row] = d;
      lbar();
      float e = 0.f;
      if (tid < RPB){
        float score = s_dot[tid] * invbk / fmaxf(s_norm[tid], 1e-12f);
        e = __expf(score - beta);
        s_e[tid] = e;
      }
      float tot = wred64(e);
      if (ln == 0 && wv < 2) s_w2[wv] = tot;
      lbar();
      if (tid == 0){
        float T = s_w2[0] + s_w2[1];
        gstore64(&wEF[b], tg | (unsigned long long)__float_as_uint(s_e[0]));
        gstore64(&wPF[b], tg | (unsigned long long)__float_as_uint(s_ww[0]));
        gstore64(&wEL[b], tg | (unsigned long long)__float_as_uint(s_e[RPB-1]));
        gstore64(&wPL[b], tg | (unsigned long long)__float_as_uint(s_ww[RPB-1]));
        atomicAdd(redD + slot * Tlen + t, fxpack(T));
      }
    }

    // ---- H-pre: poll er/ad/kr; Sw-independent reductions (quad-per-row) ----
    // mem_new = mv + ww*q, q = ad - mv*er  =>
    //   |mem_new|^2   = A0 + ww*A1 + ww^2*A2
    //   <mem_new,kr>  = B0 + ww*B1
    {
      if (tid < 256) s_er[tid] = pollw(&ppub[256 + tid], TT);          // erase (sigmoided)
      else           s_ad[tid - 256] = pollw(&ppub[512 + (tid - 256)], TT);  // add
      if (tid < 256) s_kr[tid] = pollw(&ppub[768 + tid], TT);          // keyr
      float nk2r = bred512((tid < 256) ? s_kr[tid] * s_kr[tid] : 0.f); // barriers inside
      betaR  = softplusf(s_scal[6]);
      invbkR = betaR / fmaxf(sqrtf(nk2r), 1e-12f);
      int row = tid >> 2, q = tid & 3;
      const float* mrow = &s_mem[row * Dsz];
      float mq = 0.f, qq = 0.f, qk = 0.f, mk = 0.f;
#pragma unroll
      for (int k = 0; k < 16; ++k){
        int c = (q + 4 * ((k + row) & 15)) * 4;
        float4 mv = *(const float4*)(mrow + c);
        float4 er = *(const float4*)(&s_er[c]);
        float4 ad = *(const float4*)(&s_ad[c]);
        float4 kr = *(const float4*)(&s_kr[c]);
        float qx = ad.x - mv.x * er.x;
        float qy = ad.y - mv.y * er.y;
        float qz = ad.z - mv.z * er.z;
        float qw = ad.w - mv.w * er.w;
        mq += mv.x*qx + mv.y*qy + mv.z*qz + mv.w*qw;
        qq += qx*qx + qy*qy + qz*qz + qw*qw;
        qk += qx*kr.x + qy*kr.y + qz*kr.z + qw*kr.w;
        mk += mv.x*kr.x + mv.y*kr.y + mv.z*kr.z + mv.w*kr.w;
      }
      mq = qsum4(mq); qq = qsum4(qq); qk = qsum4(qk); mk = qsum4(mk);
      if (q == 0){ s_A1[row] = 2.f*mq; s_A2[row] = qq; s_B1[row] = qk; s_B0[row] = mk; }
    }

    // ---- F: write-head shift+sharpen (S_w should already be there) ----
    {
      if (wv == 0 && ln < 4){
        const unsigned long long* bp = (ln == 0) ? &wEF[(b + 1) & (NBLK-1)]
                               : (ln == 1) ? &wPF[(b + 1) & (NBLK-1)]
                               : (ln == 2) ? &wEL[(b - 1) & (NBLK-1)]
                                           : &wPL[(b - 1) & (NBLK-1)];
        s_bd[ln] = pollw(bp, TT);
      }
      float S_w = redWait8(redD, t);
      shiftSharpen(0, s_ww, S_w, redF + slot * Tlen + t);
    }

    // ---- H-post: wait Sw; S_r fixups + publish FIRST, then mem update ----
    {
      float Sw = redWait8(redF, t);
      float invSw = 1.f / (Sw + 1e-8f);
      float4 er4 = *(const float4*)(&s_er[ln * 4]);
      float4 ad4 = *(const float4*)(&s_ad[ln * 4]);
      float e = 0.f;
      if (tid < RPB){
        float wwm = s_bw[tid] * invSw;
        s_ww[tid] = wwm;
        float A0 = s_norm[tid] * s_norm[tid];
        float n2 = fmaf(wwm, fmaf(wwm, s_A2[tid], s_A1[tid]), A0);
        float dt = fmaf(wwm, s_B1[tid], s_B0[tid]);
        float nr = sqrtf(fmaxf(n2, 0.f));
        s_norm[tid] = nr;
        float score = dt * invbkR / fmaxf(nr, 1e-12f);
        e = __expf(score - betaR);
        s_e[tid] = e;
      }
      float tot = wred64(e);
      if (ln == 0 && wv < 2) s_w2[wv] = tot;
      lbar();
      if (tid == 0){
        float T2 = s_w2[0] + s_w2[1];
        gstore64(&rEF[b], tg | (unsigned long long)__float_as_uint(s_e[0]));
        gstore64(&rPF[b], tg | (unsigned long long)__float_as_uint(s_rw[0]));
        gstore64(&rEL[b], tg | (unsigned long long)__float_as_uint(s_e[RPB-1]));
        gstore64(&rPL[b], tg | (unsigned long long)__float_as_uint(s_rw[RPB-1]));
        atomicAdd(redH + slot * Tlen + t, fxpack(T2));
      }
      // mem update runs while S_r propagates
#pragma unroll 1
      for (int it = 0; it < 16; ++it){
        int ml = it * 8 + wv;
        int off = ml * Dsz + ln * 4;
        float wwm = s_bw[ml] * invSw;
        float4 mv = *(const float4*)(&s_mem[off]);
        float4 nv;
        nv.x = fmaf(wwm, ad4.x - mv.x * er4.x, mv.x);
        nv.y = fmaf(wwm, ad4.y - mv.y * er4.y, mv.y);
        nv.z = fmaf(wwm, ad4.z - mv.z * er4.z, mv.z);
        nv.w = fmaf(wwm, ad4.w - mv.w * er4.w, mv.w);
        *(float4*)(&s_mem[off]) = nv;
      }
    }

    // ---- J: read sharpen; rvec partials; next-step GEMV hides redJ wait ----
    {
      if (wv == 0 && ln < 4){
        const unsigned long long* bp = (ln == 0) ? &rEF[(b + 1) & (NBLK-1)]
                               : (ln == 1) ? &rPF[(b + 1) & (NBLK-1)]
                               : (ln == 2) ? &rEL[(b - 1) & (NBLK-1)]
                                           : &rPL[(b - 1) & (NBLK-1)];
        s_bd[ln] = pollw(bp, TT);
      }
      float S_r = redWait8(redH, t);
      shiftSharpen(6, s_rw, S_r, nullptr);   // partial left in s_pub
      lbar();
      int col = tid & 255, half = tid >> 8;
      float acc = 0.f;
#pragma unroll 1
      for (int j = half * 64; j < half * 64 + 64; ++j) acc += s_bw[j] * s_mem[j * Dsz + col];
      if (half == 0) s_a[col] = acc;
      lbar();
      if (half == 1) atomicAdd(&Pcur[(b & (NG-1)) * 256 + col], acc + s_a[col]);
      __syncthreads();                       // drain atomics before publish
      if (tid == 0) atomicAdd(redJ + slot * Tlen + t, fxpack(s_pub));
      // hide the redJ wait under next step's x/h GEMV parts
      if (tid < 256) s_a[tid] = inputs[(size_t)(t + 1) * Isz + tid];
      lbar();
      accxh = gemvXH();
      Srcarry = redWait8(redJ, t);
    }
  }
}

extern "C" void kernel_launch(void* const* d_in, const int* in_sizes, int n_in,
                              void* d_out, int out_size, void* d_ws, size_t ws_size,
                              hipStream_t stream)
{
  (void)in_sizes; (void)out_size;
  if (n_in < 34) return;
  if (ws_size < (size_t)98304) return;
  Params P;
  for (int i = 0; i < 34; ++i) P.in[i] = (const float*)d_in[i];
  P.out = (float*)d_out;
  P.ws  = (float*)d_ws;
  hipLaunchKernelGGL(ntm_kernel, dim3(NBLK), dim3(NTHR), 0, stream, P);
}